// Round 1
// 430.786 us; speedup vs baseline: 1.0914x; 1.0914x over previous
//
#include <hip/hip_runtime.h>
#include <hip/hip_bf16.h>

typedef __bf16 bf16x8 __attribute__((ext_vector_type(8)));
typedef float floatx4 __attribute__((ext_vector_type(4)));

// RNE fp32 -> bf16 (returns raw bits)
__device__ __forceinline__ unsigned f2bf(float f) {
    unsigned u = __float_as_uint(f);
    u += 0x7FFFu + ((u >> 16) & 1u);
    return u >> 16;
}

// async global->LDS, 16 bytes per lane; LDS base must be wave-uniform,
// HW writes lane l's 16B at base + l*16. Global src address is per-lane.
__device__ __forceinline__ void gl2lds(const void* g, void* l) {
    void* gnc = const_cast<void*>(g);
    __builtin_amdgcn_global_load_lds(
        (__attribute__((address_space(1))) void*)gnc,
        (__attribute__((address_space(3))) void*)l,
        16, 0, 0);
}

// -------- fused pre-pass: cast feat+centers fp32->bf16, fp32 row norms.
__global__ __launch_bounds__(256) void cast_norm2(
    const float* __restrict__ feat, const float* __restrict__ cent,
    unsigned short* __restrict__ Ab, unsigned short* __restrict__ Bb,
    float* __restrict__ x2, float* __restrict__ c2, int M)
{
    const int tid  = threadIdx.x;
    const int half = tid >> 7;
    const int t    = tid & 127;
    const int row  = blockIdx.x * 2 + half;

    const float* src;
    unsigned short* dst;
    float* nrm;
    if (row < M) {
        src = feat + (size_t)row * 1024;
        dst = Ab   + (size_t)row * 1024;
        nrm = x2 + row;
    } else {
        const int r = row - M;
        src = cent + (size_t)r * 1024;
        dst = Bb   + (size_t)r * 1024;
        nrm = c2 + r;
    }

    const float4 v0 = ((const float4*)src)[t * 2];
    const float4 v1 = ((const float4*)src)[t * 2 + 1];
    float s = v0.x * v0.x + v0.y * v0.y + v0.z * v0.z + v0.w * v0.w
            + v1.x * v1.x + v1.y * v1.y + v1.z * v1.z + v1.w * v1.w;

    uint4 o;
    o.x = f2bf(v0.x) | (f2bf(v0.y) << 16);
    o.y = f2bf(v0.z) | (f2bf(v0.w) << 16);
    o.z = f2bf(v1.x) | (f2bf(v1.y) << 16);
    o.w = f2bf(v1.z) | (f2bf(v1.w) << 16);
    ((uint4*)dst)[t] = o;

#pragma unroll
    for (int off = 32; off > 0; off >>= 1) s += __shfl_down(s, off);
    __shared__ float ws[4];
    if ((tid & 63) == 0) ws[tid >> 6] = s;
    __syncthreads();
    if (t == 0) *nrm = ws[half * 2] + ws[half * 2 + 1];
}

// ==================== 256x256 8-phase MFMA GEMM with fused distance epilogue
// BM=BN=256, BK=64, 512 threads = 8 waves (2M x 4N), per-wave 128x64 output.
// LDS: 2 buffers x (A 32KB + B 32KB) = 128 KiB.
// Per buffer region: [2 k-panels][256 rows][32 bf16] (panel stride 16 KiB,
// row stride 64 B). st_16x32 swizzle: 16B slot index ^= ((row>>3)&1)<<1,
// applied on BOTH the ds_read address and (inverted) the global source of
// global_load_lds (LDS dest stays linear).
//
// Phase schedule per iteration (computes K-tiles T->buf0, T+1->buf1):
//   p0: rd A(b0,ks0)+B(b0,ks0); stage (T+1).B.h0->b1 | MFMA ks0 mf0-3
//   p1: rd A(b0,ks1)+B(b0,ks1); stage (T+1).B.h1->b1 | MFMA ks0 mf4-7
//   p2:                          stage (T+2).A.h0->b0 | MFMA ks1 mf0-3
//   p3:                          stage (T+2).A.h1->b0 | MFMA ks1 mf4-7  vmcnt(4)
//   p4: rd A(b1,ks0)+B(b1,ks0); stage (T+2).B.h0->b0 | MFMA ks0 mf0-3
//   p5: rd A(b1,ks1)+B(b1,ks1); stage (T+2).B.h1->b0 | MFMA ks0 mf4-7
//   p6:                          stage (T+3).A.h0->b1 | MFMA ks1 mf0-3
//   p7:                          stage (T+3).A.h1->b1 | MFMA ks1 mf4-7  vmcnt(4)
// All buffer reads are confined to the first two phases of each K-tile and
// drained by lgkmcnt(0) before that phase's end barrier, so staging issued in
// later phases can never clobber in-flight ds_reads. vmcnt(4)+barrier once per
// K-tile guarantees the next tile's 8 loads have landed (4 newest stay in
// flight across the barrier -- never vmcnt(0) in steady state).
__global__ __launch_bounds__(512, 2) void dist_gemm(
    const unsigned short* __restrict__ A,   // [M][1024] bf16 (feat)
    const unsigned short* __restrict__ B,   // [N][1024] bf16 (centers)
    const float* __restrict__ x2,           // [M]
    const float* __restrict__ c2,           // [N]
    float* __restrict__ out,                // [M][N]
    int M, int N)
{
    __shared__ alignas(16) char lds_raw[131072];
    char* ldsb = lds_raw;
    const char* ldsc = lds_raw;

    const int tid  = threadIdx.x;
    const int wave = tid >> 6;       // 0..7
    const int lane = tid & 63;
    const int quad = lane >> 4;      // 0..3
    const int l16  = lane & 15;
    const int wm   = wave >> 2;      // 0..1 (M half)
    const int wn   = wave & 3;       // 0..3 (N quarter)

    // XCD-aware mapping: XCD owns a column slab; its B slab (512 rows x 2KB
    // = 1 MB) stays L2-resident; all XCDs sweep A rows in lockstep.
    const int gx  = gridDim.x;                      // N/256, multiple of 8
    const int lin = blockIdx.y * gx + blockIdx.x;
    const int colsPerXcd = gx >> 3;
    const int xcd  = lin & 7;
    const int slot = lin >> 3;
    const int bx = xcd * colsPerXcd + (slot % colsPerXcd);
    const int by = slot / colsPerXcd;

    const int blockRow = by * 256;
    const int blockCol = bx * 256;

    // ---- staging addressing (linear LDS dest, inverse-swizzled global src)
    // lane l of wave w covers row w*16 + (l>>2), 16B slot (l&3) of a 16-row
    // x 32-col panel chunk. Source k-block = (l&3) ^ ((l>>5)<<1)  (st_16x32
    // inverse, since ((row>>3)&1) == (l>>5) here).
    const int cswz = (lane & 3) ^ (((lane >> 5) & 1) << 1);
    const unsigned short* pA = A + (size_t)(blockRow + wave * 16 + (lane >> 2)) * 1024 + cswz * 8;
    const unsigned short* pB = B + (size_t)(blockCol + wave * 16 + (lane >> 2)) * 1024 + cswz * 8;
    const int stOff = wave * 1024;   // wave-uniform LDS chunk base (bytes)

#define STAGE_A(buf, kt, h) do {                                              \
        const unsigned short* _s = pA + (size_t)(h) * 131072 + (kt) * 64;     \
        char* _d = ldsb + (buf) * 65536 + (h) * 8192 + stOff;                 \
        gl2lds(_s,      _d);                                                  \
        gl2lds(_s + 32, _d + 16384);                                          \
    } while (0)
#define STAGE_B(buf, kt, h) do {                                              \
        const unsigned short* _s = pB + (size_t)(h) * 131072 + (kt) * 64;     \
        char* _d = ldsb + (buf) * 65536 + 32768 + (h) * 8192 + stOff;         \
        gl2lds(_s,      _d);                                                  \
        gl2lds(_s + 32, _d + 16384);                                          \
    } while (0)

    // ---- fragment read addressing (swizzled)
    const int swq = quad ^ ((l16 & 8) >> 2);              // st_16x32 on read
    const int aRd = (wm * 128 + l16) * 64 + swq * 16;             // A region byte
    const int bRd = 32768 + (wn * 64 + l16) * 64 + swq * 16;      // B region byte

#define RD_A(buf, ks, mf) (*(const bf16x8*)(ldsc + (buf) * 65536 + (ks) * 16384 + (mf) * 1024 + aRd))
#define RD_B(buf, ks, nf) (*(const bf16x8*)(ldsc + (buf) * 65536 + (ks) * 16384 + (nf) * 1024 + bRd))

#define LOAD_A8(arr, buf, ks) do {                                            \
        arr[0] = RD_A(buf, ks, 0); arr[1] = RD_A(buf, ks, 1);                 \
        arr[2] = RD_A(buf, ks, 2); arr[3] = RD_A(buf, ks, 3);                 \
        arr[4] = RD_A(buf, ks, 4); arr[5] = RD_A(buf, ks, 5);                 \
        arr[6] = RD_A(buf, ks, 6); arr[7] = RD_A(buf, ks, 7);                 \
    } while (0)
#define LOAD_B4(arr, buf, ks) do {                                            \
        arr[0] = RD_B(buf, ks, 0); arr[1] = RD_B(buf, ks, 1);                 \
        arr[2] = RD_B(buf, ks, 2); arr[3] = RD_B(buf, ks, 3);                 \
    } while (0)

#define BAR()    do { __builtin_amdgcn_s_barrier(); asm volatile("" ::: "memory"); } while (0)
#define LGKM0()  asm volatile("s_waitcnt lgkmcnt(0)" ::: "memory")
#define VMCNT4() asm volatile("s_waitcnt vmcnt(4)" ::: "memory")
#define VMCNT0() asm volatile("s_waitcnt vmcnt(0)" ::: "memory")

#define MFMA16(aa, mo, bb) do {                                               \
        __builtin_amdgcn_s_setprio(1);                                        \
        _Pragma("unroll")                                                     \
        for (int _m = 0; _m < 4; ++_m) {                                      \
            _Pragma("unroll")                                                 \
            for (int _n = 0; _n < 4; ++_n) {                                  \
                acc[(mo) + _m][_n] = __builtin_amdgcn_mfma_f32_16x16x32_bf16( \
                    aa[(mo) + _m], bb[_n], acc[(mo) + _m][_n], 0, 0, 0);      \
            }                                                                 \
        }                                                                     \
        __builtin_amdgcn_s_setprio(0);                                        \
    } while (0)

    floatx4 acc[8][4];
#pragma unroll
    for (int i = 0; i < 8; ++i)
#pragma unroll
        for (int j = 0; j < 4; ++j) acc[i][j] = (floatx4){0.f, 0.f, 0.f, 0.f};

    bf16x8 a0[8], a1[8], b0[4], b1[4];

    // ---- prologue: tile0 (A+B) -> buf0, tile1 A -> buf1; leave tile1.A in flight
    STAGE_A(0, 0, 0); STAGE_A(0, 0, 1);
    STAGE_B(0, 0, 0); STAGE_B(0, 0, 1);
    STAGE_A(1, 1, 0); STAGE_A(1, 1, 1);
    VMCNT4();
    BAR();

#define K_ITER(T, S) do {                                                     \
        /* p0 */                                                              \
        LOAD_A8(a0, 0, 0); LOAD_B4(b0, 0, 0);                                 \
        STAGE_B(1, (T) + 1, 0);                                               \
        BAR(); LGKM0(); MFMA16(a0, 0, b0); BAR();                             \
        /* p1 */                                                              \
        LOAD_A8(a1, 0, 1); LOAD_B4(b1, 0, 1);                                 \
        STAGE_B(1, (T) + 1, 1);                                               \
        BAR(); LGKM0(); MFMA16(a0, 4, b0); BAR();                             \
        /* p2 */                                                              \
        if (S) STAGE_A(0, (T) + 2, 0);                                        \
        BAR(); MFMA16(a1, 0, b1); BAR();                                      \
        /* p3 */                                                              \
        if (S) STAGE_A(0, (T) + 2, 1);                                        \
        BAR(); MFMA16(a1, 4, b1);                                             \
        if (S) { VMCNT4(); } else { VMCNT0(); }                               \
        BAR();                                                                \
        /* p4 */                                                              \
        LOAD_A8(a0, 1, 0); LOAD_B4(b0, 1, 0);                                 \
        if (S) STAGE_B(0, (T) + 2, 0);                                        \
        BAR(); LGKM0(); MFMA16(a0, 0, b0); BAR();                             \
        /* p5 */                                                              \
        LOAD_A8(a1, 1, 1); LOAD_B4(b1, 1, 1);                                 \
        if (S) STAGE_B(0, (T) + 2, 1);                                        \
        BAR(); LGKM0(); MFMA16(a0, 4, b0); BAR();                             \
        /* p6 */                                                              \
        if (S) STAGE_A(1, (T) + 3, 0);                                        \
        BAR(); MFMA16(a1, 0, b1); BAR();                                      \
        /* p7 */                                                              \
        if (S) STAGE_A(1, (T) + 3, 1);                                        \
        BAR(); MFMA16(a1, 4, b1); VMCNT4(); BAR();                            \
    } while (0)

    // K = 1024 -> 16 K-tiles -> 8 iterations; last iteration peeled (no
    // out-of-range staging; full drain at its p3 since tile15.B just issued).
#pragma unroll 1
    for (int it = 0; it < 7; ++it) {
        const int T = it * 2;
        K_ITER(T, true);
    }
    K_ITER(14, false);

    // ---- epilogue: dist = x2[row] + c2[col] - 2*xc
    // C/D layout: col = lane&15, row = quad*4 + reg. Plain stores (L2 merges).
    float c2v[4];
#pragma unroll
    for (int nf = 0; nf < 4; ++nf) c2v[nf] = c2[blockCol + wn * 64 + nf * 16 + l16];

#pragma unroll
    for (int mf = 0; mf < 8; ++mf) {
        const int rowb = blockRow + wm * 128 + mf * 16 + quad * 4;
        float x2v[4];
#pragma unroll
        for (int r = 0; r < 4; ++r) x2v[r] = x2[rowb + r];
#pragma unroll
        for (int nf = 0; nf < 4; ++nf) {
            const int col = blockCol + wn * 64 + nf * 16 + l16;
            float* o = out + (size_t)rowb * N + col;
#pragma unroll
            for (int r = 0; r < 4; ++r)
                o[(size_t)r * N] = fmaf(-2.0f, acc[mf][nf][r], x2v[r] + c2v[nf]);
        }
    }

#undef K_ITER
#undef MFMA16
#undef VMCNT0
#undef VMCNT4
#undef LGKM0
#undef BAR
#undef LOAD_B4
#undef LOAD_A8
#undef RD_B
#undef RD_A
#undef STAGE_B
#undef STAGE_A
}

// -------- fallback (only if ws_size too small / shape mismatch)
__global__ __launch_bounds__(256) void dist_fallback(
    const float* __restrict__ A, const float* __restrict__ B,
    float* __restrict__ out, int M, int N, int K)
{
    __shared__ float sA[64][17];
    __shared__ float sB[64][17];
    const int tid = threadIdx.x;
    const int tx = tid & 15;
    const int ty = tid >> 4;
    const int rowBase = blockIdx.y * 64;
    const int colBase = blockIdx.x * 64;
    float acc[4][4] = {};
    for (int k0 = 0; k0 < K; k0 += 16) {
        __syncthreads();
        {
            const int r = tid >> 2, c = (tid & 3) * 4;
            float4 va = *(const float4*)(A + (size_t)(rowBase + r) * K + k0 + c);
            sA[r][c] = va.x; sA[r][c + 1] = va.y; sA[r][c + 2] = va.z; sA[r][c + 3] = va.w;
            float4 vb = *(const float4*)(B + (size_t)(colBase + r) * K + k0 + c);
            sB[r][c] = vb.x; sB[r][c + 1] = vb.y; sB[r][c + 2] = vb.z; sB[r][c + 3] = vb.w;
        }
        __syncthreads();
#pragma unroll
        for (int kk = 0; kk < 16; kk++) {
            float ra[4], rb[4];
#pragma unroll
            for (int i = 0; i < 4; i++) ra[i] = sA[ty * 4 + i][kk];
#pragma unroll
            for (int j = 0; j < 4; j++) rb[j] = sB[tx * 4 + j][kk];
#pragma unroll
            for (int i = 0; i < 4; i++)
#pragma unroll
                for (int j = 0; j < 4; j++) {
                    float d = ra[i] - rb[j];
                    acc[i][j] = fmaf(d, d, acc[i][j]);
                }
        }
    }
#pragma unroll
    for (int i = 0; i < 4; i++)
#pragma unroll
        for (int j = 0; j < 4; j++)
            out[(size_t)(rowBase + ty * 4 + i) * N + (colBase + tx * 4 + j)] = acc[i][j];
}

extern "C" void kernel_launch(void* const* d_in, const int* in_sizes, int n_in,
                              void* d_out, int out_size, void* d_ws, size_t ws_size,
                              hipStream_t stream) {
    const float* feat = (const float*)d_in[0];
    const float* cent = (const float*)d_in[1];
    float* out = (float*)d_out;

    const int D = 1024;
    const int M = in_sizes[0] / D;   // 16384
    const int N = in_sizes[1] / D;   // 4096

    const size_t offA  = 0;
    const size_t offB  = offA + (size_t)M * D * sizeof(unsigned short);
    const size_t offX2 = offB + (size_t)N * D * sizeof(unsigned short);
    const size_t offC2 = offX2 + (size_t)M * sizeof(float);
    const size_t need  = offC2 + (size_t)N * sizeof(float);

    // new path needs M%256==0 (row tiles), N%2048==0 (col tiles divisible by 8
    // XCDs), D==1024 (hardcoded K), and the bf16 workspace.
    if (ws_size >= need && (M % 256) == 0 && (N % 2048) == 0) {
        unsigned short* Ab = (unsigned short*)((char*)d_ws + offA);
        unsigned short* Bb = (unsigned short*)((char*)d_ws + offB);
        float* x2 = (float*)((char*)d_ws + offX2);
        float* c2 = (float*)((char*)d_ws + offC2);

        cast_norm2<<<(M + N) / 2, 256, 0, stream>>>(feat, cent, Ab, Bb, x2, c2, M);
        dist_gemm<<<dim3(N / 256, M / 256), 512, 0, stream>>>(Ab, Bb, x2, c2, out, M, N);
    } else {
        dist_fallback<<<dim3(N / 64, M / 64), 256, 0, stream>>>(feat, cent, out, M, N, D);
    }
}

// Round 2
// 430.616 us; speedup vs baseline: 1.0918x; 1.0004x over previous
//
#include <hip/hip_runtime.h>
#include <hip/hip_bf16.h>

typedef __bf16 bf16x8 __attribute__((ext_vector_type(8)));
typedef float floatx4 __attribute__((ext_vector_type(4)));

// RNE fp32 -> bf16 (returns raw bits)
__device__ __forceinline__ unsigned f2bf(float f) {
    unsigned u = __float_as_uint(f);
    u += 0x7FFFu + ((u >> 16) & 1u);
    return u >> 16;
}

// async global->LDS, 16 bytes per lane; LDS base must be wave-uniform,
// HW writes lane l's 16B at base + l*16. Global src address is per-lane.
__device__ __forceinline__ void gl2lds(const void* g, void* l) {
    void* gnc = const_cast<void*>(g);
    __builtin_amdgcn_global_load_lds(
        (__attribute__((address_space(1))) void*)gnc,
        (__attribute__((address_space(3))) void*)l,
        16, 0, 0);
}

// -------- fused pre-pass: cast feat+centers fp32->bf16, fp32 row norms.
// One WAVE per row, no LDS, no __syncthreads: lane reads 4x float4 (fully
// coalesced 1 KiB/wave per step), packs bf16 pairs, uint2 stores (512 B/wave),
// shuffle-only norm reduce. Pure-BW kernel: ~126 MB -> ~20 us target.
__global__ __launch_bounds__(256) void cast_norm2(
    const float* __restrict__ feat, const float* __restrict__ cent,
    unsigned short* __restrict__ Ab, unsigned short* __restrict__ Bb,
    float* __restrict__ x2, float* __restrict__ c2, int M)
{
    const int wave = threadIdx.x >> 6;
    const int lane = threadIdx.x & 63;
    const int row  = blockIdx.x * 4 + wave;

    const float* src;
    unsigned short* dst;
    float* nrm;
    if (row < M) {
        src = feat + (size_t)row * 1024;
        dst = Ab   + (size_t)row * 1024;
        nrm = x2 + row;
    } else {
        const int r = row - M;
        src = cent + (size_t)r * 1024;
        dst = Bb   + (size_t)r * 1024;
        nrm = c2 + r;
    }

    const float4* s4 = (const float4*)src;   // 256 float4 per row
    uint2* d2 = (uint2*)dst;                 // 256 uint2 per row
    float s = 0.f;
#pragma unroll
    for (int j = 0; j < 4; ++j) {
        const float4 v = s4[j * 64 + lane];
        s += v.x * v.x + v.y * v.y + v.z * v.z + v.w * v.w;
        uint2 o;
        o.x = f2bf(v.x) | (f2bf(v.y) << 16);
        o.y = f2bf(v.z) | (f2bf(v.w) << 16);
        d2[j * 64 + lane] = o;
    }
#pragma unroll
    for (int off = 32; off > 0; off >>= 1) s += __shfl_down(s, off);
    if (lane == 0) *nrm = s;
}

// ==================== 256x256 8-phase MFMA GEMM with fused distance epilogue
// BM=BN=256, BK=64, 512 threads = 8 waves (2M x 4N), per-wave 128x64 output.
// LDS: 2 buffers x (A 32KB + B 32KB) = 128 KiB.
// Per buffer region: [2 k-panels][256 rows][32 bf16] (panel stride 16 KiB,
// row stride 64 B). st_16x32 swizzle: 16B slot ^= ((row>>3)&1)<<1, applied on
// the ds_read address and (inverted) on the global source of global_load_lds
// (LDS dest stays linear).
//
// QUADRANT phase schedule (template-style: <=16 live frags = 64 VGPR, reads
// spread 12/4/8/0 per phase). Per K-tile T in buffer `buf` (4 phases):
//   p0: rd aF=A[mf0-3][2ks](8) + bL=B[nf0-1][2ks](4); stage B(obuf,T+1,h0)
//       | MFMA Q00 = acc[0-3][0-1]
//   p1: rd bH=B[nf2-3][2ks](4);                        stage B(obuf,T+1,h1)
//       | MFMA Q01 = acc[0-3][2-3]
//   p2: rd aF=A[mf4-7][2ks](8)                         | MFMA Q11 = acc[4-7][2-3]
//   p3: stage A(buf,T+2) (4 loads; safe: all buf-A reads drained by p2's
//       lgkmcnt(0)+barrier)                            | MFMA Q10 = acc[4-7][0-1]
//       then vmcnt(4) -- drains everything tile T+1 needs, leaves the 4
//       newest (A(buf,T+2)) in flight. Never vmcnt(0) in steady state.
__global__ __launch_bounds__(512, 2) void dist_gemm(
    const unsigned short* __restrict__ A,   // [M][1024] bf16 (feat)
    const unsigned short* __restrict__ B,   // [N][1024] bf16 (centers)
    const float* __restrict__ x2,           // [M]
    const float* __restrict__ c2,           // [N]
    float* __restrict__ out,                // [M][N]
    int M, int N)
{
    __shared__ alignas(16) char lds_raw[131072];
    char* ldsb = lds_raw;
    const char* ldsc = lds_raw;

    const int tid  = threadIdx.x;
    const int wave = tid >> 6;       // 0..7
    const int lane = tid & 63;
    const int quad = lane >> 4;      // 0..3
    const int l16  = lane & 15;
    const int wm   = wave >> 2;      // 0..1 (M half)
    const int wn   = wave & 3;       // 0..3 (N quarter)

    // XCD-aware mapping: XCD owns a column slab; its B slab stays L2-resident;
    // all 8 XCDs sweep A rows in lockstep (A bf16 = 33.6 MB, L3-resident).
    const int gx  = gridDim.x;                      // N/256, multiple of 8
    const int lin = blockIdx.y * gx + blockIdx.x;
    const int colsPerXcd = gx >> 3;
    const int xcd  = lin & 7;
    const int slot = lin >> 3;
    const int bx = xcd * colsPerXcd + (slot % colsPerXcd);
    const int by = slot / colsPerXcd;

    const int blockRow = by * 256;
    const int blockCol = bx * 256;

    // ---- staging addressing (linear LDS dest, inverse-swizzled global src)
    const int cswz = (lane & 3) ^ (((lane >> 5) & 1) << 1);
    const unsigned short* pA = A + (size_t)(blockRow + wave * 16 + (lane >> 2)) * 1024 + cswz * 8;
    const unsigned short* pB = B + (size_t)(blockCol + wave * 16 + (lane >> 2)) * 1024 + cswz * 8;
    const int stOff = wave * 1024;   // wave-uniform LDS chunk base (bytes)

// STAGE_A: both 128-row halves, both k-panels -> 4 gl2lds
#define STAGE_A(buf, kt) do {                                                 \
        const unsigned short* _s0 = pA + (size_t)(kt) * 64;                   \
        const unsigned short* _s1 = _s0 + 131072;                             \
        char* _d0 = ldsb + (buf) * 65536 + stOff;                             \
        gl2lds(_s0,      _d0);                                                \
        gl2lds(_s0 + 32, _d0 + 16384);                                        \
        gl2lds(_s1,      _d0 + 8192);                                         \
        gl2lds(_s1 + 32, _d0 + 8192 + 16384);                                 \
    } while (0)
// STAGE_B: one 128-row half (h) -> 2 gl2lds
#define STAGE_B(buf, kt, h) do {                                              \
        const unsigned short* _s = pB + (size_t)(h) * 131072 + (kt) * 64;     \
        char* _d = ldsb + (buf) * 65536 + 32768 + (h) * 8192 + stOff;         \
        gl2lds(_s,      _d);                                                  \
        gl2lds(_s + 32, _d + 16384);                                          \
    } while (0)

    // ---- fragment read addressing (st_16x32 swizzle on read)
    const int swq = quad ^ ((l16 & 8) >> 2);
    const int aRd = (wm * 128 + l16) * 64 + swq * 16;             // A region byte
    const int bRd = 32768 + (wn * 64 + l16) * 64 + swq * 16;      // B region byte

#define RD_A(buf, ks, mf) (*(const bf16x8*)(ldsc + (buf) * 65536 + (ks) * 16384 + (mf) * 1024 + aRd))
#define RD_B(buf, ks, nf) (*(const bf16x8*)(ldsc + (buf) * 65536 + (ks) * 16384 + (nf) * 1024 + bRd))

// aF[mf*2+ks], 8 reads (one A-quadrant, both k-panels)
#define LDA8(buf, mo) do {                                                    \
        aF[0] = RD_A(buf, 0, (mo) + 0); aF[2] = RD_A(buf, 0, (mo) + 1);       \
        aF[4] = RD_A(buf, 0, (mo) + 2); aF[6] = RD_A(buf, 0, (mo) + 3);       \
        aF[1] = RD_A(buf, 1, (mo) + 0); aF[3] = RD_A(buf, 1, (mo) + 1);       \
        aF[5] = RD_A(buf, 1, (mo) + 2); aF[7] = RD_A(buf, 1, (mo) + 3);       \
    } while (0)
// bb[nf*2+ks], 4 reads (one B-pair, both k-panels)
#define LDB4(bb, buf, no) do {                                                \
        bb[0] = RD_B(buf, 0, (no) + 0); bb[2] = RD_B(buf, 0, (no) + 1);       \
        bb[1] = RD_B(buf, 1, (no) + 0); bb[3] = RD_B(buf, 1, (no) + 1);       \
    } while (0)

#define BAR()    do { __builtin_amdgcn_s_barrier(); asm volatile("" ::: "memory"); } while (0)
#define LGKM0()  asm volatile("s_waitcnt lgkmcnt(0)" ::: "memory")
#define VMCNT4() asm volatile("s_waitcnt vmcnt(4)" ::: "memory")
#define VMCNT0() asm volatile("s_waitcnt vmcnt(0)" ::: "memory")

// one C-quadrant x K=64: 4 mf x 2 nf x 2 ks = 16 MFMA
#define MFMA_Q(mo, no, bb) do {                                               \
        __builtin_amdgcn_s_setprio(1);                                        \
        _Pragma("unroll")                                                     \
        for (int _m = 0; _m < 4; ++_m) {                                      \
            _Pragma("unroll")                                                 \
            for (int _n = 0; _n < 2; ++_n) {                                  \
                _Pragma("unroll")                                             \
                for (int _k = 0; _k < 2; ++_k) {                              \
                    acc[(mo) + _m][(no) + _n] =                               \
                        __builtin_amdgcn_mfma_f32_16x16x32_bf16(              \
                            aF[_m * 2 + _k], bb[_n * 2 + _k],                 \
                            acc[(mo) + _m][(no) + _n], 0, 0, 0);              \
                }                                                             \
            }                                                                 \
        }                                                                     \
        __builtin_amdgcn_s_setprio(0);                                        \
    } while (0)

    floatx4 acc[8][4];
#pragma unroll
    for (int i = 0; i < 8; ++i)
#pragma unroll
        for (int j = 0; j < 4; ++j) acc[i][j] = (floatx4){0.f, 0.f, 0.f, 0.f};

    bf16x8 aF[8], bL[4], bH[4];

// Half-iteration: compute tile in `buf`; stage B(obuf,tB) at p0/p1,
// A(buf,tA) at p3. SB/SA gate the stages; LASTVM replaces vmcnt(4) when !SA.
#define HALF(buf, obuf, tB, tA, SB, SA, LASTVM) do {                          \
        /* p0 */                                                              \
        LDA8(buf, 0); LDB4(bL, buf, 0);                                       \
        if (SB) STAGE_B(obuf, tB, 0);                                         \
        BAR(); LGKM0(); MFMA_Q(0, 0, bL); BAR();                              \
        /* p1 */                                                              \
        LDB4(bH, buf, 2);                                                     \
        if (SB) STAGE_B(obuf, tB, 1);                                         \
        BAR(); LGKM0(); MFMA_Q(0, 2, bH); BAR();                              \
        /* p2 */                                                              \
        LDA8(buf, 4);                                                         \
        BAR(); LGKM0(); MFMA_Q(4, 2, bH); BAR();                              \
        /* p3 */                                                              \
        if (SA) STAGE_A(buf, tA);                                             \
        BAR(); MFMA_Q(4, 0, bL);                                              \
        if (SA) { VMCNT4(); } else { LASTVM; }                                \
        BAR();                                                                \
    } while (0)

    // ---- prologue: tile0 (A+B) -> buf0, tile1 A -> buf1; A(1,1) stays in flight
    STAGE_A(0, 0);
    STAGE_B(0, 0, 0); STAGE_B(0, 0, 1);
    STAGE_A(1, 1);
    VMCNT4();
    BAR();

    // K = 1024 -> 16 K-tiles -> 7 full double-iterations + peeled tail.
#pragma unroll 1
    for (int it = 0; it < 7; ++it) {
        const int T = it * 2;
        HALF(0, 1, T + 1, T + 2, true, true, (void)0);
        HALF(1, 0, T + 2, T + 3, true, true, (void)0);
    }
    // tail: tile14 stages B(1,15) then fully drains; tile15 stages nothing.
    HALF(0, 1, 15, 0, true, false, VMCNT0());
    HALF(1, 0, 0, 0, false, false, (void)0);

    // ---- epilogue: dist = x2[row] + c2[col] - 2*xc
    // C/D layout: col = lane&15, row = quad*4 + reg. Plain stores (L2 merges;
    // round-0 WRITE_SIZE was exactly the 262 MB ideal; NT regressed).
    float c2v[4];
#pragma unroll
    for (int nf = 0; nf < 4; ++nf) c2v[nf] = c2[blockCol + wn * 64 + nf * 16 + l16];

#pragma unroll
    for (int mf = 0; mf < 8; ++mf) {
        const int rowb = blockRow + wm * 128 + mf * 16 + quad * 4;
        float x2v[4];
#pragma unroll
        for (int r = 0; r < 4; ++r) x2v[r] = x2[rowb + r];
#pragma unroll
        for (int nf = 0; nf < 4; ++nf) {
            const int col = blockCol + wn * 64 + nf * 16 + l16;
            float* o = out + (size_t)rowb * N + col;
#pragma unroll
            for (int r = 0; r < 4; ++r)
                o[(size_t)r * N] = fmaf(-2.0f, acc[mf][nf][r], x2v[r] + c2v[nf]);
        }
    }

#undef HALF
#undef MFMA_Q
#undef VMCNT0
#undef VMCNT4
#undef LGKM0
#undef BAR
#undef LDB4
#undef LDA8
#undef RD_B
#undef RD_A
#undef STAGE_B
#undef STAGE_A
}

// -------- fallback (only if ws_size too small / shape mismatch)
__global__ __launch_bounds__(256) void dist_fallback(
    const float* __restrict__ A, const float* __restrict__ B,
    float* __restrict__ out, int M, int N, int K)
{
    __shared__ float sA[64][17];
    __shared__ float sB[64][17];
    const int tid = threadIdx.x;
    const int tx = tid & 15;
    const int ty = tid >> 4;
    const int rowBase = blockIdx.y * 64;
    const int colBase = blockIdx.x * 64;
    float acc[4][4] = {};
    for (int k0 = 0; k0 < K; k0 += 16) {
        __syncthreads();
        {
            const int r = tid >> 2, c = (tid & 3) * 4;
            float4 va = *(const float4*)(A + (size_t)(rowBase + r) * K + k0 + c);
            sA[r][c] = va.x; sA[r][c + 1] = va.y; sA[r][c + 2] = va.z; sA[r][c + 3] = va.w;
            float4 vb = *(const float4*)(B + (size_t)(colBase + r) * K + k0 + c);
            sB[r][c] = vb.x; sB[r][c + 1] = vb.y; sB[r][c + 2] = vb.z; sB[r][c + 3] = vb.w;
        }
        __syncthreads();
#pragma unroll
        for (int kk = 0; kk < 16; kk++) {
            float ra[4], rb[4];
#pragma unroll
            for (int i = 0; i < 4; i++) ra[i] = sA[ty * 4 + i][kk];
#pragma unroll
            for (int j = 0; j < 4; j++) rb[j] = sB[tx * 4 + j][kk];
#pragma unroll
            for (int i = 0; i < 4; i++)
#pragma unroll
                for (int j = 0; j < 4; j++) {
                    float d = ra[i] - rb[j];
                    acc[i][j] = fmaf(d, d, acc[i][j]);
                }
        }
    }
#pragma unroll
    for (int i = 0; i < 4; i++)
#pragma unroll
        for (int j = 0; j < 4; j++)
            out[(size_t)(rowBase + ty * 4 + i) * N + (colBase + tx * 4 + j)] = acc[i][j];
}

extern "C" void kernel_launch(void* const* d_in, const int* in_sizes, int n_in,
                              void* d_out, int out_size, void* d_ws, size_t ws_size,
                              hipStream_t stream) {
    const float* feat = (const float*)d_in[0];
    const float* cent = (const float*)d_in[1];
    float* out = (float*)d_out;

    const int D = 1024;
    const int M = in_sizes[0] / D;   // 16384
    const int N = in_sizes[1] / D;   // 4096

    const size_t offA  = 0;
    const size_t offB  = offA + (size_t)M * D * sizeof(unsigned short);
    const size_t offX2 = offB + (size_t)N * D * sizeof(unsigned short);
    const size_t offC2 = offX2 + (size_t)M * sizeof(float);
    const size_t need  = offC2 + (size_t)N * sizeof(float);

    if (ws_size >= need && (M % 256) == 0 && (N % 2048) == 0) {
        unsigned short* Ab = (unsigned short*)((char*)d_ws + offA);
        unsigned short* Bb = (unsigned short*)((char*)d_ws + offB);
        float* x2 = (float*)((char*)d_ws + offX2);
        float* c2 = (float*)((char*)d_ws + offC2);

        cast_norm2<<<(M + N) / 4, 256, 0, stream>>>(feat, cent, Ab, Bb, x2, c2, M);
        dist_gemm<<<dim3(N / 256, M / 256), 512, 0, stream>>>(Ab, Bb, x2, c2, out, M, N);
    } else {
        dist_fallback<<<dim3(N / 64, M / 64), 256, 0, stream>>>(feat, cent, out, M, N, D);
    }
}

// Round 3
// 427.485 us; speedup vs baseline: 1.0998x; 1.0073x over previous
//
#include <hip/hip_runtime.h>
#include <hip/hip_bf16.h>

typedef __bf16 bf16x8 __attribute__((ext_vector_type(8)));
typedef float floatx4 __attribute__((ext_vector_type(4)));

// RNE fp32 -> bf16 (returns raw bits)
__device__ __forceinline__ unsigned f2bf(float f) {
    unsigned u = __float_as_uint(f);
    u += 0x7FFFu + ((u >> 16) & 1u);
    return u >> 16;
}

// async global->LDS, 16 bytes per lane; LDS base must be wave-uniform,
// HW writes lane l's 16B at base + l*16. Global src address is per-lane.
__device__ __forceinline__ void gl2lds(const void* g, void* l) {
    void* gnc = const_cast<void*>(g);
    __builtin_amdgcn_global_load_lds(
        (__attribute__((address_space(1))) void*)gnc,
        (__attribute__((address_space(3))) void*)l,
        16, 0, 0);
}

// -------- fused pre-pass: cast feat+centers fp32->bf16, fp32 row norms.
// One WAVE per row, no LDS, no __syncthreads.
__global__ __launch_bounds__(256) void cast_norm2(
    const float* __restrict__ feat, const float* __restrict__ cent,
    unsigned short* __restrict__ Ab, unsigned short* __restrict__ Bb,
    float* __restrict__ x2, float* __restrict__ c2, int M)
{
    const int wave = threadIdx.x >> 6;
    const int lane = threadIdx.x & 63;
    const int row  = blockIdx.x * 4 + wave;

    const float* src;
    unsigned short* dst;
    float* nrm;
    if (row < M) {
        src = feat + (size_t)row * 1024;
        dst = Ab   + (size_t)row * 1024;
        nrm = x2 + row;
    } else {
        const int r = row - M;
        src = cent + (size_t)r * 1024;
        dst = Bb   + (size_t)r * 1024;
        nrm = c2 + r;
    }

    const float4* s4 = (const float4*)src;   // 256 float4 per row
    uint2* d2 = (uint2*)dst;                 // 256 uint2 per row
    float s = 0.f;
#pragma unroll
    for (int j = 0; j < 4; ++j) {
        const float4 v = s4[j * 64 + lane];
        s += v.x * v.x + v.y * v.y + v.z * v.z + v.w * v.w;
        uint2 o;
        o.x = f2bf(v.x) | (f2bf(v.y) << 16);
        o.y = f2bf(v.z) | (f2bf(v.w) << 16);
        d2[j * 64 + lane] = o;
    }
#pragma unroll
    for (int off = 32; off > 0; off >>= 1) s += __shfl_down(s, off);
    if (lane == 0) *nrm = s;
}

// ==================== 256x256 MFMA GEMM with fused distance epilogue
// BM=BN=256, BK=64, 512 threads = 8 waves (2M x 4N), per-wave 128x64 output.
// LDS: 2 buffers x (A 32KB + B 32KB) = 128 KiB.
// Per buffer region: [2 k-panels][256 rows][32 bf16] (panel stride 16 KiB,
// row stride 64 B = 4 slots of 16B).
//
// FULL-SPREAD swizzle (round-3 change): slot = quad ^ ((row>>1)&3).
// Quarter-wave (16 lanes, one quad) bank spread: start bank =
// (row&1)*16 + slot*4 -> 8 distinct bank-quads x 2 lanes = 2 dwords/bank
// over all 32 banks (floor). Previous half-spread ((row>>3)&1)<<1 left a
// quarter-wave on 16 banks (4 dwords/bank = 2x floor). Staging keeps LDS
// dest linear (global_load_lds requirement) and inverse-swizzles the
// per-lane GLOBAL source chunk: cswz = (lane&3) ^ ((lane>>3)&3), since the
// covered row is lane>>2 (row bits 1..2 = lane bits 3..4).
//
// MINIMAL-BARRIER phase schedule (round-3 change): one s_barrier per phase
// END (4/K-tile, was 8). Safety argument:
//   - MFMA depends only on this wave's own ds_reads -> per-wave lgkmcnt(0).
//   - STAGE_A(buf) at p3 overwrites buf-A, last read at p2; p2's end-barrier
//     happens after every wave passed its own lgkmcnt(0) -> all reads done.
//   - STAGE_B(obuf) at p0/p1 overwrites obuf-B, last read at p1 of the
//     previous tile in obuf, published by that tile's end barrier.
//   - Reads of a fresh tile need ALL waves' staging landed: per-wave
//     vmcnt(4) gate (own loads) + tile-end barrier (publishes everyone's).
__global__ __launch_bounds__(512, 2) void dist_gemm(
    const unsigned short* __restrict__ A,   // [M][1024] bf16 (feat)
    const unsigned short* __restrict__ B,   // [N][1024] bf16 (centers)
    const float* __restrict__ x2,           // [M]
    const float* __restrict__ c2,           // [N]
    float* __restrict__ out,                // [M][N]
    int M, int N)
{
    __shared__ alignas(16) char lds_raw[131072];
    char* ldsb = lds_raw;
    const char* ldsc = lds_raw;

    const int tid  = threadIdx.x;
    const int wave = tid >> 6;       // 0..7
    const int lane = tid & 63;
    const int quad = lane >> 4;      // 0..3
    const int l16  = lane & 15;
    const int wm   = wave >> 2;      // 0..1 (M half)
    const int wn   = wave & 3;       // 0..3 (N quarter)

    // XCD-aware mapping: XCD owns a column slab; its B slab stays L2-resident;
    // all 8 XCDs sweep A rows in lockstep (A bf16 = 33.6 MB, L3-resident).
    const int gx  = gridDim.x;                      // N/256, multiple of 8
    const int lin = blockIdx.y * gx + blockIdx.x;
    const int colsPerXcd = gx >> 3;
    const int xcd  = lin & 7;
    const int slot = lin >> 3;
    const int bx = xcd * colsPerXcd + (slot % colsPerXcd);
    const int by = slot / colsPerXcd;

    const int blockRow = by * 256;
    const int blockCol = bx * 256;

    // ---- staging addressing (linear LDS dest, inverse-swizzled global src)
    // LDS(row, s) holds global k-chunk s ^ ((row>>1)&3).
    const int cswz = (lane & 3) ^ ((lane >> 3) & 3);
    const unsigned short* pA = A + (size_t)(blockRow + wave * 16 + (lane >> 2)) * 1024 + cswz * 8;
    const unsigned short* pB = B + (size_t)(blockCol + wave * 16 + (lane >> 2)) * 1024 + cswz * 8;
    const int stOff = wave * 1024;   // wave-uniform LDS chunk base (bytes)

// STAGE_A: both 128-row halves, both k-panels -> 4 gl2lds
#define STAGE_A(buf, kt) do {                                                 \
        const unsigned short* _s0 = pA + (size_t)(kt) * 64;                   \
        const unsigned short* _s1 = _s0 + 131072;                             \
        char* _d0 = ldsb + (buf) * 65536 + stOff;                             \
        gl2lds(_s0,      _d0);                                                \
        gl2lds(_s0 + 32, _d0 + 16384);                                        \
        gl2lds(_s1,      _d0 + 8192);                                         \
        gl2lds(_s1 + 32, _d0 + 8192 + 16384);                                 \
    } while (0)
// STAGE_B: one 128-row half (h) -> 2 gl2lds
#define STAGE_B(buf, kt, h) do {                                              \
        const unsigned short* _s = pB + (size_t)(h) * 131072 + (kt) * 64;     \
        char* _d = ldsb + (buf) * 65536 + 32768 + (h) * 8192 + stOff;         \
        gl2lds(_s,      _d);                                                  \
        gl2lds(_s + 32, _d + 16384);                                          \
    } while (0)

    // ---- fragment read addressing (full-spread swizzle on read)
    const int swq = quad ^ ((l16 >> 1) & 3);
    const int aRd = (wm * 128 + l16) * 64 + swq * 16;             // A region byte
    const int bRd = 32768 + (wn * 64 + l16) * 64 + swq * 16;      // B region byte

#define RD_A(buf, ks, mf) (*(const bf16x8*)(ldsc + (buf) * 65536 + (ks) * 16384 + (mf) * 1024 + aRd))
#define RD_B(buf, ks, nf) (*(const bf16x8*)(ldsc + (buf) * 65536 + (ks) * 16384 + (nf) * 1024 + bRd))

// aF[mf*2+ks], 8 reads (one A-quadrant, both k-panels)
#define LDA8(buf, mo) do {                                                    \
        aF[0] = RD_A(buf, 0, (mo) + 0); aF[2] = RD_A(buf, 0, (mo) + 1);       \
        aF[4] = RD_A(buf, 0, (mo) + 2); aF[6] = RD_A(buf, 0, (mo) + 3);       \
        aF[1] = RD_A(buf, 1, (mo) + 0); aF[3] = RD_A(buf, 1, (mo) + 1);       \
        aF[5] = RD_A(buf, 1, (mo) + 2); aF[7] = RD_A(buf, 1, (mo) + 3);       \
    } while (0)
// bb[nf*2+ks], 4 reads (one B-pair, both k-panels)
#define LDB4(bb, buf, no) do {                                                \
        bb[0] = RD_B(buf, 0, (no) + 0); bb[2] = RD_B(buf, 0, (no) + 1);       \
        bb[1] = RD_B(buf, 1, (no) + 0); bb[3] = RD_B(buf, 1, (no) + 1);       \
    } while (0)

#define BAR()    do { __builtin_amdgcn_s_barrier(); asm volatile("" ::: "memory"); } while (0)
#define LGKM0()  asm volatile("s_waitcnt lgkmcnt(0)" ::: "memory")
#define VMCNT4() asm volatile("s_waitcnt vmcnt(4)" ::: "memory")
#define VMCNT0() asm volatile("s_waitcnt vmcnt(0)" ::: "memory")

// one C-quadrant x K=64: 4 mf x 2 nf x 2 ks = 16 MFMA
#define MFMA_Q(mo, no, bb) do {                                               \
        __builtin_amdgcn_s_setprio(1);                                        \
        _Pragma("unroll")                                                     \
        for (int _m = 0; _m < 4; ++_m) {                                      \
            _Pragma("unroll")                                                 \
            for (int _n = 0; _n < 2; ++_n) {                                  \
                _Pragma("unroll")                                             \
                for (int _k = 0; _k < 2; ++_k) {                              \
                    acc[(mo) + _m][(no) + _n] =                               \
                        __builtin_amdgcn_mfma_f32_16x16x32_bf16(              \
                            aF[_m * 2 + _k], bb[_n * 2 + _k],                 \
                            acc[(mo) + _m][(no) + _n], 0, 0, 0);              \
                }                                                             \
            }                                                                 \
        }                                                                     \
        __builtin_amdgcn_s_setprio(0);                                        \
    } while (0)

    floatx4 acc[8][4];
#pragma unroll
    for (int i = 0; i < 8; ++i)
#pragma unroll
        for (int j = 0; j < 4; ++j) acc[i][j] = (floatx4){0.f, 0.f, 0.f, 0.f};

    bf16x8 aF[8], bL[4], bH[4];

// Half-iteration: compute tile in `buf`; stage B(obuf,tB) at p0/p1,
// A(buf,tA) at p3. One barrier per phase END (see header comment).
#define HALF(buf, obuf, tB, tA, SB, SA, LASTVM) do {                          \
        /* p0 */                                                              \
        LDA8(buf, 0); LDB4(bL, buf, 0);                                       \
        if (SB) STAGE_B(obuf, tB, 0);                                         \
        LGKM0(); MFMA_Q(0, 0, bL); BAR();                                     \
        /* p1 */                                                              \
        LDB4(bH, buf, 2);                                                     \
        if (SB) STAGE_B(obuf, tB, 1);                                         \
        LGKM0(); MFMA_Q(0, 2, bH); BAR();                                     \
        /* p2 */                                                              \
        LDA8(buf, 4);                                                         \
        LGKM0(); MFMA_Q(4, 2, bH); BAR();                                     \
        /* p3 */                                                              \
        if (SA) STAGE_A(buf, tA);                                             \
        MFMA_Q(4, 0, bL);                                                     \
        if (SA) { VMCNT4(); } else { LASTVM; }                                \
        BAR();                                                                \
    } while (0)

    // ---- prologue: tile0 (A+B) -> buf0, tile1 A -> buf1; A(1,1) stays in flight
    STAGE_A(0, 0);
    STAGE_B(0, 0, 0); STAGE_B(0, 0, 1);
    STAGE_A(1, 1);
    VMCNT4();
    BAR();

    // K = 1024 -> 16 K-tiles -> 7 full double-iterations + peeled tail.
#pragma unroll 1
    for (int it = 0; it < 7; ++it) {
        const int T = it * 2;
        HALF(0, 1, T + 1, T + 2, true, true, (void)0);
        HALF(1, 0, T + 2, T + 3, true, true, (void)0);
    }
    // tail: tile14 stages B(1,15) then fully drains; tile15 stages nothing.
    HALF(0, 1, 15, 0, true, false, VMCNT0());
    HALF(1, 0, 0, 0, false, false, (void)0);

    // ---- epilogue: dist = x2[row] + c2[col] - 2*xc
    // C/D layout: col = lane&15, row = quad*4 + reg. Plain stores (L2 merges;
    // round-0 WRITE_SIZE was exactly the 262 MB ideal; NT regressed).
    float c2v[4];
#pragma unroll
    for (int nf = 0; nf < 4; ++nf) c2v[nf] = c2[blockCol + wn * 64 + nf * 16 + l16];

#pragma unroll
    for (int mf = 0; mf < 8; ++mf) {
        const int rowb = blockRow + wm * 128 + mf * 16 + quad * 4;
        float x2v[4];
#pragma unroll
        for (int r = 0; r < 4; ++r) x2v[r] = x2[rowb + r];
#pragma unroll
        for (int nf = 0; nf < 4; ++nf) {
            const int col = blockCol + wn * 64 + nf * 16 + l16;
            float* o = out + (size_t)rowb * N + col;
#pragma unroll
            for (int r = 0; r < 4; ++r)
                o[(size_t)r * N] = fmaf(-2.0f, acc[mf][nf][r], x2v[r] + c2v[nf]);
        }
    }

#undef HALF
#undef MFMA_Q
#undef VMCNT0
#undef VMCNT4
#undef LGKM0
#undef BAR
#undef LDB4
#undef LDA8
#undef RD_B
#undef RD_A
#undef STAGE_B
#undef STAGE_A
}

// -------- fallback (only if ws_size too small / shape mismatch)
__global__ __launch_bounds__(256) void dist_fallback(
    const float* __restrict__ A, const float* __restrict__ B,
    float* __restrict__ out, int M, int N, int K)
{
    __shared__ float sA[64][17];
    __shared__ float sB[64][17];
    const int tid = threadIdx.x;
    const int tx = tid & 15;
    const int ty = tid >> 4;
    const int rowBase = blockIdx.y * 64;
    const int colBase = blockIdx.x * 64;
    float acc[4][4] = {};
    for (int k0 = 0; k0 < K; k0 += 16) {
        __syncthreads();
        {
            const int r = tid >> 2, c = (tid & 3) * 4;
            float4 va = *(const float4*)(A + (size_t)(rowBase + r) * K + k0 + c);
            sA[r][c] = va.x; sA[r][c + 1] = va.y; sA[r][c + 2] = va.z; sA[r][c + 3] = va.w;
            float4 vb = *(const float4*)(B + (size_t)(colBase + r) * K + k0 + c);
            sB[r][c] = vb.x; sB[r][c + 1] = vb.y; sB[r][c + 2] = vb.z; sB[r][c + 3] = vb.w;
        }
        __syncthreads();
#pragma unroll
        for (int kk = 0; kk < 16; kk++) {
            float ra[4], rb[4];
#pragma unroll
            for (int i = 0; i < 4; i++) ra[i] = sA[ty * 4 + i][kk];
#pragma unroll
            for (int j = 0; j < 4; j++) rb[j] = sB[tx * 4 + j][kk];
#pragma unroll
            for (int i = 0; i < 4; i++)
#pragma unroll
                for (int j = 0; j < 4; j++) {
                    float d = ra[i] - rb[j];
                    acc[i][j] = fmaf(d, d, acc[i][j]);
                }
        }
    }
#pragma unroll
    for (int i = 0; i < 4; i++)
#pragma unroll
        for (int j = 0; j < 4; j++)
            out[(size_t)(rowBase + ty * 4 + i) * N + (colBase + tx * 4 + j)] = acc[i][j];
}

extern "C" void kernel_launch(void* const* d_in, const int* in_sizes, int n_in,
                              void* d_out, int out_size, void* d_ws, size_t ws_size,
                              hipStream_t stream) {
    const float* feat = (const float*)d_in[0];
    const float* cent = (const float*)d_in[1];
    float* out = (float*)d_out;

    const int D = 1024;
    const int M = in_sizes[0] / D;   // 16384
    const int N = in_sizes[1] / D;   // 4096

    const size_t offA  = 0;
    const size_t offB  = offA + (size_t)M * D * sizeof(unsigned short);
    const size_t offX2 = offB + (size_t)N * D * sizeof(unsigned short);
    const size_t offC2 = offX2 + (size_t)M * sizeof(float);
    const size_t need  = offC2 + (size_t)N * sizeof(float);

    if (ws_size >= need && (M % 256) == 0 && (N % 2048) == 0) {
        unsigned short* Ab = (unsigned short*)((char*)d_ws + offA);
        unsigned short* Bb = (unsigned short*)((char*)d_ws + offB);
        float* x2 = (float*)((char*)d_ws + offX2);
        float* c2 = (float*)((char*)d_ws + offC2);

        cast_norm2<<<(M + N) / 4, 256, 0, stream>>>(feat, cent, Ab, Bb, x2, c2, M);
        dist_gemm<<<dim3(N / 256, M / 256), 512, 0, stream>>>(Ab, Bb, x2, c2, out, M, N);
    } else {
        dist_fallback<<<dim3(N / 64, M / 64), 256, 0, stream>>>(feat, cent, out, M, N, D);
    }
}